// Round 6
// baseline (127.206 us; speedup 1.0000x reference)
//
#include <hip/hip_runtime.h>
#include <hip/hip_bf16.h>
#include <stdint.h>

#define N_PTS   4096
#define M_CODES 4096
#define ZDIM    1024
// fp8 tiled layout: elem (r,k) at seg(rb)*16384 + kg*128 + r16*8 + ke  (BYTES)
//   rb=r>>4, r16=r&15, kg=k>>3, ke=k&7. Chunk (rb,kg) = 16 rows x 8 k = 128 B.
//   Seg = 16 rows x 1024 k x 1 B = 16 KB.

typedef __attribute__((ext_vector_type(4))) float f32x4;
typedef __attribute__((ext_vector_type(8))) int   i32x8;

__device__ __forceinline__ unsigned enc_f32(float f) {
    unsigned u = __float_as_uint(f);
    return (u & 0x80000000u) ? ~u : (u | 0x80000000u);
}
__device__ __forceinline__ float dec_f32(unsigned e) {
    unsigned u = (e & 0x80000000u) ? (e ^ 0x80000000u) : ~e;
    return __uint_as_float(u);
}

// ---------------------------------------------------------------------------
// prep: fp32 -> fp8 e4m3 (OCP) + tiled layout + row sum-of-squares (fp32,
// pre-quantization — error enters as 2(e.dz+z.de), sigma~2 << 35.5 threshold).
// One block = 16 rows. grid 512 (256 z + 256 e).
// ---------------------------------------------------------------------------
#define PREP_PITCH_B 1040   // bytes per LDS row: 1024 + 16 pad
__global__ __launch_bounds__(256) void prep_kernel(
    const float* __restrict__ z, const float* __restrict__ e,
    uint8_t* __restrict__ zb, uint8_t* __restrict__ eb,
    float* __restrict__ zsq, float* __restrict__ esq,
    unsigned* __restrict__ min_enc) {
    __shared__ uint8_t tile[16 * PREP_PITCH_B];   // ~16.6 KB
    __shared__ float redbuf[16 * 4];

    const int t = threadIdx.x;
    const int b = blockIdx.x;
    if (b < 16) min_enc[b * 256 + t] = 0xFFFFFFFFu;

    const bool is_z = b < 256;
    const int rb = b & 255;
    const float* src = (is_z ? z : e) + (size_t)rb * 16 * ZDIM;
    uint8_t* dst = (is_z ? zb : eb) + (size_t)rb * 16384;   // 16 KB seg
    const int w = t >> 6, lane = t & 63;

    // Phase 1: coalesced loads, fp32 row sums (R8-proven reduction),
    // pack 4 floats -> 4 fp8 into one dword in LDS.
    #pragma unroll
    for (int it = 0; it < 16; it++) {
        float4 v = reinterpret_cast<const float4*>(src + (size_t)it * ZDIM)[t];
        int pk = 0;
        pk = __builtin_amdgcn_cvt_pk_fp8_f32(v.x, v.y, pk, false);
        pk = __builtin_amdgcn_cvt_pk_fp8_f32(v.z, v.w, pk, true);
        *reinterpret_cast<int*>(&tile[it * PREP_PITCH_B + t * 4]) = pk;
        float s = v.x * v.x + v.y * v.y + v.z * v.z + v.w * v.w;
        #pragma unroll
        for (int off = 1; off < 64; off <<= 1) s += __shfl_xor(s, off, 64);
        if (lane == 0) redbuf[it * 4 + w] = s;
    }
    __syncthreads();

    // Phase 2: transpose-store to tiled global (chunk c -> dst + c*8, linear).
    #pragma unroll
    for (int it2 = 0; it2 < 8; it2++) {
        const int c = it2 * 256 + t;          // 0..2047
        const int kg = c >> 4, r16 = c & 15;
        const unsigned long long val = *reinterpret_cast<const unsigned long long*>(
            &tile[r16 * PREP_PITCH_B + kg * 8]);
        *reinterpret_cast<unsigned long long*>(&dst[(size_t)c * 8]) = val;
    }
    if (t < 16) {
        float sq = redbuf[t * 4] + redbuf[t * 4 + 1] +
                   redbuf[t * 4 + 2] + redbuf[t * 4 + 3];
        const int row = rb * 16 + t;
        if (is_z) zsq[row] = sq; else esq[row] = sq;
    }
}

// ---------------------------------------------------------------------------
// gemm_min: R5 counted-vmcnt pipeline + MX MFMA. R5 proved the barrier drain
// was the mask (106.8 µs total, gemm ~26 µs); with the stall removed the
// dominant term is now the 16x16x32 fp8 MFMA floor (~16.6 µs at bf16 rate).
// This round halves it: mfma_scale_f32_16x16x128_f8f6f4, unit e8m0 scales
// (0x7F = 2^0), identical e4m3 math at ~2x rate (R3-verified numerics).
// Pipeline (R5 pattern at K-stage=128):
//   * 3 x 16 KB LDS buffers, DMA prefetch depth 2 (DMA(st+2) during
//     compute(st)); 8 stages.
//   * Raw s_barrier + counted `s_waitcnt vmcnt(4)` at stage boundaries —
//     DMA(st+2)'s 4 loads stay in flight across the barrier; FIFO vmcnt
//     retires DMA(st+1) (older) => buf(st+1) ready. Never drain to 0
//     mid-loop (m218). st=6 boundary drains (last DMA is DMA(7)).
//   * B loads issued FIRST each stage (sched_barrier(0) pin) so their
//     compiler waits don't drain the DMA prefetch.
//   * WAR safety: DMA(st+2) writes buf((st+2)%3)=buf((st-1)%3), whose
//     readers all passed the st-1 boundary barrier before issue.
// Registers: acc 64 + 4 B i32x8 frags 32 + A frag 8 + addr ~30 ~= 135-150
// -> __launch_bounds__(256,3) (cap ~170; R3 verified spill-free at this
// pressure). LDS 48 KB -> 3 blocks/CU (144 KB). Watch WRITE_SIZE for spill.
// Fragment layout 16x16x128: lane l = row (l&15), k = (l>>4)*32 + j; tiled:
// 4x 8B at q*512 + p*128 + r16*8. C/D = 16x16 shape layout -> epilogue
// unchanged (proven). 256 thr = 4 waves (2x2 of 64x64), grid (32,32).
// ---------------------------------------------------------------------------
__global__ __launch_bounds__(256, 3) void gemm_min_kernel(
    const uint8_t* __restrict__ zb, const uint8_t* __restrict__ eb,
    const float* __restrict__ zsq, unsigned* __restrict__ min_enc) {
    __shared__ __align__(16) uint8_t As[3 * 16384];  // 3 bufs x (8 segs x 2 KB)
    __shared__ float zsq_s[128];
    __shared__ float colmin[2][128];

    const int t = threadIdx.x;        // 0..255
    const int bx = blockIdx.x;        // code (col) block
    const int by = blockIdx.y;        // point (row) block
    const int lane = t & 63;
    const int w = t >> 6;             // 0..3
    const int wm = w >> 1, wn = w & 1;
    const int lrow = lane & 15;       // r16: frag row index
    const int q = lane >> 4;          // 0..3: k-group within fragment

    if (t < 128) zsq_s[t] = zsq[by * 128 + t];

    f32x4 acc[4][4];
    #pragma unroll
    for (int i = 0; i < 4; i++)
        #pragma unroll
        for (int j = 0; j < 4; j++) acc[i][j] = (f32x4){0.f, 0.f, 0.f, 0.f};

    // A staging: per stage 16 KB (8 segs x 2 KB run). Instr j (0..3) = 4 KB:
    // waves {0,1} -> seg 2j, waves {2,3} -> seg 2j+1; inner = (t&127)*16.
    const int seg_half = t >> 7;            // 0..1
    const int inner = (t & 127) * 16;       // byte offset in 2 KB run
    const size_t a_seg0 = (size_t)(by * 8) * 16384;

    // Per-lane fragment byte offset within one seg's 2 KB K-stage window:
    // lane l needs k = q*32 + p*8 + ke  ->  bytes at q*512 + p*128 + r16*8.
    const int frag_off = q * 512 + lrow * 8;
    const uint8_t* b_frag =
        eb + (size_t)(bx * 8 + wn * 4) * 16384 + frag_off;

#define DMA_STAGE(st_)                                                        \
    {                                                                         \
        const int buf_ = ((st_) % 3) * 16384;                                 \
        const int koff_ = (st_) * 2048;  /* byte offset within seg */         \
        _Pragma("unroll")                                                     \
        for (int j = 0; j < 4; j++) {                                         \
            const int seg_ = j * 2 + seg_half;                                \
            const uint8_t* ga = zb + a_seg0 +                                 \
                (size_t)seg_ * 16384 + koff_ + inner;                         \
            __builtin_amdgcn_global_load_lds(                                 \
                (const __attribute__((address_space(1))) void*)ga,            \
                (__attribute__((address_space(3))) void*)(As + buf_ +         \
                    seg_ * 2048 + inner), 16, 0, 0);                          \
        }                                                                     \
    }

    // Assemble i32x8 fragment from 4x 8B loads (constant-index inserts only;
    // SROA-safe — R1/R2 lesson).
#define LOAD_FRAG(dst_, base_)                                                \
    {                                                                         \
        const int2 d0_ = *(const int2*)((base_));                             \
        const int2 d1_ = *(const int2*)((base_) + 128);                       \
        const int2 d2_ = *(const int2*)((base_) + 256);                       \
        const int2 d3_ = *(const int2*)((base_) + 384);                       \
        dst_[0] = d0_.x; dst_[1] = d0_.y;                                     \
        dst_[2] = d1_.x; dst_[3] = d1_.y;                                     \
        dst_[4] = d2_.x; dst_[5] = d2_.y;                                     \
        dst_[6] = d3_.x; dst_[7] = d3_.y;                                     \
    }

#define MXMFMA(a_, b_, c_)                                                    \
    __builtin_amdgcn_mfma_scale_f32_16x16x128_f8f6f4(                         \
        (a_), (b_), (c_), 0, 0, 0, 0x7F7F7F7F, 0, 0x7F7F7F7F)

    // Prologue: fill depth-2 pipe; wait DMA(0) only (DMA(1) stays in flight).
    DMA_STAGE(0);
    DMA_STAGE(1);
    asm volatile("s_waitcnt vmcnt(4)" ::: "memory");
    __builtin_amdgcn_s_barrier();

    #pragma unroll
    for (int st = 0; st < 8; st++) {
        const int buf = (st % 3) * 16384;
        const int koff = st * 2048;

        // B fragments (K=128) — FIRST, so their compiler waits never drain
        // the DMA prefetch queue.
        i32x8 bf0, bf1, bf2, bf3;
        LOAD_FRAG(bf0, b_frag + (size_t)0 * 16384 + koff);
        LOAD_FRAG(bf1, b_frag + (size_t)1 * 16384 + koff);
        LOAD_FRAG(bf2, b_frag + (size_t)2 * 16384 + koff);
        LOAD_FRAG(bf3, b_frag + (size_t)3 * 16384 + koff);
        __builtin_amdgcn_sched_barrier(0);   // pin B loads above DMA

        if (st < 6) DMA_STAGE(st + 2);       // depth-2 prefetch

        // Compute stage st from buf: stream A fragments, 4 MX MFMAs each.
        #pragma unroll
        for (int am = 0; am < 4; am++) {
            i32x8 af;
            LOAD_FRAG(af, As + buf + (wm * 4 + am) * 2048 + frag_off);
            acc[am][0] = MXMFMA(af, bf0, acc[am][0]);
            acc[am][1] = MXMFMA(af, bf1, acc[am][1]);
            acc[am][2] = MXMFMA(af, bf2, acc[am][2]);
            acc[am][3] = MXMFMA(af, bf3, acc[am][3]);
        }

        // Stage boundary: counted wait (DMA(st+2) stays in flight), raw
        // barrier. st==6: drain DMA(7) fully (no DMA(8) exists).
        if (st < 7) {
            __builtin_amdgcn_sched_barrier(0);
            if (st < 6) {
                asm volatile("s_waitcnt vmcnt(4)" ::: "memory");
            } else {
                asm volatile("s_waitcnt vmcnt(0)" ::: "memory");
            }
            __builtin_amdgcn_s_barrier();
            __builtin_amdgcn_sched_barrier(0);
        }
    }
#undef DMA_STAGE
#undef LOAD_FRAG
#undef MXMFMA

    __syncthreads();

    // Epilogue (proven; C/D layout shape-determined): row = q*4+r, col = lrow.
    #pragma unroll
    for (int an = 0; an < 4; an++) {
        float v = 3.4e38f;
        #pragma unroll
        for (int am = 0; am < 4; am++) {
            const int rbase = wm * 64 + am * 16 + q * 4;
            f32x4 c = acc[am][an];
            v = fminf(v, zsq_s[rbase + 0] - 2.f * c[0]);
            v = fminf(v, zsq_s[rbase + 1] - 2.f * c[1]);
            v = fminf(v, zsq_s[rbase + 2] - 2.f * c[2]);
            v = fminf(v, zsq_s[rbase + 3] - 2.f * c[3]);
        }
        v = fminf(v, __shfl_xor(v, 16, 64));
        v = fminf(v, __shfl_xor(v, 32, 64));
        if (q == 0) colmin[wm][wn * 64 + an * 16 + lrow] = v;
    }
    __syncthreads();
    if (t < 128) {
        const float m = fminf(colmin[0][t], colmin[1][t]);
        atomicMin(&min_enc[bx * 128 + t], enc_f32(m));
    }
}

// ---------------------------------------------------------------------------
// finalize: mean_j (dec(min_enc[j]) + esq[j]) -> single fp32 scalar.
// ---------------------------------------------------------------------------
__global__ __launch_bounds__(256) void finalize_kernel(
    const unsigned* __restrict__ min_enc, const float* __restrict__ esq,
    float* __restrict__ out) {
    const int t = threadIdx.x;
    float s = 0.f;
    #pragma unroll
    for (int i = 0; i < M_CODES / 256; i++) {
        const int j = i * 256 + t;
        s += dec_f32(min_enc[j]) + esq[j];
    }
    #pragma unroll
    for (int off = 1; off < 64; off <<= 1) s += __shfl_xor(s, off, 64);
    __shared__ float red[4];
    if ((t & 63) == 0) red[t >> 6] = s;
    __syncthreads();
    if (t == 0) out[0] = (red[0] + red[1] + red[2] + red[3]) * (1.f / M_CODES);
}

extern "C" void kernel_launch(void* const* d_in, const int* in_sizes, int n_in,
                              void* d_out, int out_size, void* d_ws, size_t ws_size,
                              hipStream_t stream) {
    (void)in_sizes; (void)n_in; (void)out_size; (void)ws_size;
    const float* z = (const float*)d_in[0];
    const float* e = (const float*)d_in[1];
    char* ws = (char*)d_ws;
    uint8_t* zb = (uint8_t*)ws;                                          // 4 MB
    uint8_t* eb = (uint8_t*)(ws + ((size_t)4 << 20));                    // 4 MB
    float* zsq = (float*)(ws + ((size_t)8 << 20));                       // 16 KB
    float* esq = (float*)(ws + ((size_t)8 << 20) + 16384);               // 16 KB
    unsigned* min_enc = (unsigned*)(ws + ((size_t)8 << 20) + 32768);     // 16 KB

    prep_kernel<<<dim3(512), dim3(256), 0, stream>>>(
        z, e, zb, eb, zsq, esq, min_enc);
    gemm_min_kernel<<<dim3(32, 32), dim3(256), 0, stream>>>(
        zb, eb, zsq, min_enc);
    finalize_kernel<<<dim3(1), dim3(256), 0, stream>>>(min_enc, esq, (float*)d_out);
}

// Round 7
// 103.988 us; speedup vs baseline: 1.2233x; 1.2233x over previous
//
#include <hip/hip_runtime.h>
#include <hip/hip_bf16.h>
#include <stdint.h>

#define N_PTS   4096
#define M_CODES 4096
#define ZDIM    1024
// fp8 tiled layout: elem (r,k) at seg(rb)*16384 + kg*128 + r16*8 + ke  (BYTES)
//   rb=r>>4, r16=r&15, kg=k>>3, ke=k&7. Chunk (rb,kg) = 16 rows x 8 k = 128 B.
//   Seg = 16 rows x 1024 k x 1 B = 16 KB.

typedef __attribute__((ext_vector_type(4)))  float f32x4;
typedef __attribute__((ext_vector_type(16))) float f32x16;
typedef __attribute__((ext_vector_type(8)))  int   i32x8;

__device__ __forceinline__ unsigned enc_f32(float f) {
    unsigned u = __float_as_uint(f);
    return (u & 0x80000000u) ? ~u : (u | 0x80000000u);
}
__device__ __forceinline__ float dec_f32(unsigned e) {
    unsigned u = (e & 0x80000000u) ? (e ^ 0x80000000u) : ~e;
    return __uint_as_float(u);
}

// ---------------------------------------------------------------------------
// prep: fp32 -> fp8 e4m3 (OCP) + tiled layout + row sum-of-squares (fp32,
// pre-quantization — error enters as 2(e.dz+z.de), sigma~2 << 35.5 threshold).
// One block = 16 rows. grid 512 (256 z + 256 e).
// ---------------------------------------------------------------------------
#define PREP_PITCH_B 1040   // bytes per LDS row: 1024 + 16 pad
__global__ __launch_bounds__(256) void prep_kernel(
    const float* __restrict__ z, const float* __restrict__ e,
    uint8_t* __restrict__ zb, uint8_t* __restrict__ eb,
    float* __restrict__ zsq, float* __restrict__ esq,
    unsigned* __restrict__ min_enc) {
    __shared__ uint8_t tile[16 * PREP_PITCH_B];   // ~16.6 KB
    __shared__ float redbuf[16 * 4];

    const int t = threadIdx.x;
    const int b = blockIdx.x;
    if (b < 16) min_enc[b * 256 + t] = 0xFFFFFFFFu;

    const bool is_z = b < 256;
    const int rb = b & 255;
    const float* src = (is_z ? z : e) + (size_t)rb * 16 * ZDIM;
    uint8_t* dst = (is_z ? zb : eb) + (size_t)rb * 16384;   // 16 KB seg
    const int w = t >> 6, lane = t & 63;

    // Phase 1: coalesced loads, fp32 row sums (R8-proven reduction),
    // pack 4 floats -> 4 fp8 into one dword in LDS.
    #pragma unroll
    for (int it = 0; it < 16; it++) {
        float4 v = reinterpret_cast<const float4*>(src + (size_t)it * ZDIM)[t];
        int pk = 0;
        pk = __builtin_amdgcn_cvt_pk_fp8_f32(v.x, v.y, pk, false);
        pk = __builtin_amdgcn_cvt_pk_fp8_f32(v.z, v.w, pk, true);
        *reinterpret_cast<int*>(&tile[it * PREP_PITCH_B + t * 4]) = pk;
        float s = v.x * v.x + v.y * v.y + v.z * v.z + v.w * v.w;
        #pragma unroll
        for (int off = 1; off < 64; off <<= 1) s += __shfl_xor(s, off, 64);
        if (lane == 0) redbuf[it * 4 + w] = s;
    }
    __syncthreads();

    // Phase 2: transpose-store to tiled global (chunk c -> dst + c*8, linear).
    #pragma unroll
    for (int it2 = 0; it2 < 8; it2++) {
        const int c = it2 * 256 + t;          // 0..2047
        const int kg = c >> 4, r16 = c & 15;
        const unsigned long long val = *reinterpret_cast<const unsigned long long*>(
            &tile[r16 * PREP_PITCH_B + kg * 8]);
        *reinterpret_cast<unsigned long long*>(&dst[(size_t)c * 8]) = val;
    }
    if (t < 16) {
        float sq = redbuf[t * 4] + redbuf[t * 4 + 1] +
                   redbuf[t * 4 + 2] + redbuf[t * 4 + 3];
        const int row = rb * 16 + t;
        if (is_z) zsq[row] = sq; else esq[row] = sq;
    }
}

// ---------------------------------------------------------------------------
// gemm_min: R5 champion pipeline (UNCHANGED: 16 stages, 3 x 8 KB triple
// buffer, depth-2 DMA prefetch, counted `s_waitcnt vmcnt(2)` + raw s_barrier
// boundaries, B-loads-first pinning) with the compute core swapped to
// mfma_scale_f32_32x32x64_f8f6f4 (unit e8m0 scales 0x7F = 2^0; identical
// e4m3 math at the ~4.7 PF MX rate).
// R6 lesson: HW VGPR quantum is coarse (occupancy steps 64/128/256, m69) so
// (256,3) still caps at 128 regs; the 16x16x128 MX operand set (acc 64 +
// 4x8 B-frags + 8 A + addr ~= 140) can't fit -> spilled (37 MB scratch).
// The 32x32x64 shape fixes the economics at the SAME MX rate: 64x64 wave
// tile = 2x2 of 32x32 -> acc 4 x f32x16 = 64, only TWO live 8-reg B frags
// (16), one streamed A frag (8), addr ~20 -> ~110 < 128 -> (256,4), 4
// blocks/CU, no spill. Per stage: 4 MFMAs (~69 cyc/wave, was 155 for
// 16x16x32) with the same 8 ds_read_b64 + 8 global-8B + 2 DMA loads.
// Operand layout 32x32x64 f8f6f4 (analogue of the HW-verified 16x16x128):
//   lane l: row = l&31, k = (l>>5)*32 + j (j=0..31 dense bytes). In tiled
//   layout: seg_sel=(l&31)>>4, bytes at seg_sel*SEG + (l>>5)*512 + p*128 +
//   (l&15)*8, p=0..3 -> LOAD_FRAG (4x 8B at +0/128/256/384) unchanged.
// C/D 32x32 (shape-determined incl. scaled, m128/m74/m101): col = lane&31,
//   row = (reg&3) + 8*(reg>>2) + 4*(lane>>5).
// 256 thr = 4 waves (2x2 of 64x64 => 128x128 block), grid (32,32).
// ---------------------------------------------------------------------------
__global__ __launch_bounds__(256, 4) void gemm_min_kernel(
    const uint8_t* __restrict__ zb, const uint8_t* __restrict__ eb,
    const float* __restrict__ zsq, unsigned* __restrict__ min_enc) {
    __shared__ __align__(16) uint8_t As[3 * 8192];   // 3 bufs x (8 segs x 1 KB)
    __shared__ float zsq_s[128];
    __shared__ float colmin[2][128];

    const int t = threadIdx.x;        // 0..255
    const int bx = blockIdx.x;        // code (col) block
    const int by = blockIdx.y;        // point (row) block
    const int lane = t & 63;
    const int w = t >> 6;             // 0..3
    const int wm = w >> 1, wn = w & 1;
    const int hi = lane >> 5;         // K-half selector (and C/D row offset)

    if (t < 128) zsq_s[t] = zsq[by * 128 + t];

    f32x16 acc[2][2];
    #pragma unroll
    for (int i = 0; i < 2; i++)
        #pragma unroll
        for (int j = 0; j < 2; j++)
            #pragma unroll
            for (int r = 0; r < 16; r++) acc[i][j][r] = 0.f;

    const size_t a_seg0 = (size_t)(by * 8) * 16384;

    // Per-lane operand offset within a seg's 1 KB K-stage window:
    // lane l: k = (l>>5)*32 + p*8 + ke -> (l>>5)*512 + p*128 + (l&15)*8;
    // rows 16..31 of the 32-row block live one seg over (seg_sel).
    const int seg_sel = (lane & 31) >> 4;
    const int op_off  = hi * 512 + (lane & 15) * 8;

    // A (LDS): frag base for (wm, am) = buf + (wm*4 + am*2 + seg_sel)*1024
    //          + op_off (+ p*128 inside LOAD_FRAG).
    const int a_off = seg_sel * 1024 + op_off;

    // B (global): wave wn's 64-col panel; an adds 2 segs (32 KB).
    const uint8_t* b_frag =
        eb + (size_t)(bx * 8 + wn * 4 + seg_sel) * 16384 + op_off;

    // A staging per stage: 8 segs x 1 KB runs (seg's K-window st*1024).
    // 2 instrs x 256 thr x 16 B = 8 KB. Instr j: wave w -> seg j*4+w.
#define DMA_STAGE(st_)                                                        \
    {                                                                         \
        const int buf_ = ((st_) % 3) * 8192;                                  \
        _Pragma("unroll")                                                     \
        for (int j = 0; j < 2; j++) {                                         \
            const int seg_ = j * 4 + w;                                       \
            const uint8_t* ga = zb + a_seg0 + (size_t)seg_ * 16384 +          \
                (st_) * 1024 + lane * 16;                                     \
            __builtin_amdgcn_global_load_lds(                                 \
                (const __attribute__((address_space(1))) void*)ga,            \
                (__attribute__((address_space(3))) void*)(As + buf_ +         \
                    seg_ * 1024 + lane * 16), 16, 0, 0);                      \
        }                                                                     \
    }

    // Assemble i32x8 fragment from 4x 8B loads (constant-index inserts only;
    // SROA-safe — R1/R2 lesson).
#define LOAD_FRAG(dst_, base_)                                                \
    {                                                                         \
        const int2 d0_ = *(const int2*)((base_));                             \
        const int2 d1_ = *(const int2*)((base_) + 128);                       \
        const int2 d2_ = *(const int2*)((base_) + 256);                       \
        const int2 d3_ = *(const int2*)((base_) + 384);                       \
        dst_[0] = d0_.x; dst_[1] = d0_.y;                                     \
        dst_[2] = d1_.x; dst_[3] = d1_.y;                                     \
        dst_[4] = d2_.x; dst_[5] = d2_.y;                                     \
        dst_[6] = d3_.x; dst_[7] = d3_.y;                                     \
    }

#define MXMFMA(a_, b_, c_)                                                    \
    __builtin_amdgcn_mfma_scale_f32_32x32x64_f8f6f4(                          \
        (a_), (b_), (c_), 0, 0, 0, 0x7F7F7F7F, 0, 0x7F7F7F7F)

    // Prologue: fill depth-2 pipe; wait DMA(0) only (DMA(1) stays in flight).
    DMA_STAGE(0);
    DMA_STAGE(1);
    asm volatile("s_waitcnt vmcnt(2)" ::: "memory");
    __builtin_amdgcn_s_barrier();

    #pragma unroll
    for (int st = 0; st < 16; st++) {
        const int buf = (st % 3) * 8192;
        const int koff = st * 1024;

        // B fragments (K=64, both an panels) — FIRST, so their compiler
        // waits never drain the DMA prefetch queue.
        i32x8 bf0, bf1;
        LOAD_FRAG(bf0, b_frag + koff);
        LOAD_FRAG(bf1, b_frag + 32768 + koff);
        __builtin_amdgcn_sched_barrier(0);   // pin B loads above DMA

        if (st < 14) DMA_STAGE(st + 2);      // depth-2 prefetch

        // Compute stage st from buf: stream A fragments, 2 MX MFMAs each.
        #pragma unroll
        for (int am = 0; am < 2; am++) {
            i32x8 af;
            LOAD_FRAG(af, As + buf + (wm * 4 + am * 2) * 1024 + a_off);
            acc[am][0] = MXMFMA(af, bf0, acc[am][0]);
            acc[am][1] = MXMFMA(af, bf1, acc[am][1]);
        }

        // Stage boundary: counted wait (DMA(st+2) stays in flight), raw
        // barrier. st==14: drain DMA(15) fully (no DMA(16) exists).
        if (st < 15) {
            __builtin_amdgcn_sched_barrier(0);
            if (st < 14) {
                asm volatile("s_waitcnt vmcnt(2)" ::: "memory");
            } else {
                asm volatile("s_waitcnt vmcnt(0)" ::: "memory");
            }
            __builtin_amdgcn_s_barrier();
            __builtin_amdgcn_sched_barrier(0);
        }
    }
#undef DMA_STAGE
#undef LOAD_FRAG
#undef MXMFMA

    __syncthreads();

    // Epilogue, 32x32 C/D layout: col = lane&31, row = (r&3)+8*(r>>2)+4*hi.
    // Per an-panel: min over both am blocks' 16 regs, then lane^32 pairs
    // (other 16 rows), then cross-wm via colmin LDS + atomicMin.
    #pragma unroll
    for (int an = 0; an < 2; an++) {
        float v = 3.4e38f;
        #pragma unroll
        for (int am = 0; am < 2; am++) {
            const int rbase = wm * 64 + am * 32 + hi * 4;
            f32x16 c = acc[am][an];
            #pragma unroll
            for (int r = 0; r < 16; r++) {
                const int row = (r & 3) + 8 * (r >> 2);
                v = fminf(v, zsq_s[rbase + row] - 2.f * c[r]);
            }
        }
        v = fminf(v, __shfl_xor(v, 32, 64));
        if (hi == 0) colmin[wm][wn * 64 + an * 32 + (lane & 31)] = v;
    }
    __syncthreads();
    if (t < 128) {
        const float m = fminf(colmin[0][t], colmin[1][t]);
        atomicMin(&min_enc[bx * 128 + t], enc_f32(m));
    }
}

// ---------------------------------------------------------------------------
// finalize: mean_j (dec(min_enc[j]) + esq[j]) -> single fp32 scalar.
// ---------------------------------------------------------------------------
__global__ __launch_bounds__(256) void finalize_kernel(
    const unsigned* __restrict__ min_enc, const float* __restrict__ esq,
    float* __restrict__ out) {
    const int t = threadIdx.x;
    float s = 0.f;
    #pragma unroll
    for (int i = 0; i < M_CODES / 256; i++) {
        const int j = i * 256 + t;
        s += dec_f32(min_enc[j]) + esq[j];
    }
    #pragma unroll
    for (int off = 1; off < 64; off <<= 1) s += __shfl_xor(s, off, 64);
    __shared__ float red[4];
    if ((t & 63) == 0) red[t >> 6] = s;
    __syncthreads();
    if (t == 0) out[0] = (red[0] + red[1] + red[2] + red[3]) * (1.f / M_CODES);
}

extern "C" void kernel_launch(void* const* d_in, const int* in_sizes, int n_in,
                              void* d_out, int out_size, void* d_ws, size_t ws_size,
                              hipStream_t stream) {
    (void)in_sizes; (void)n_in; (void)out_size; (void)ws_size;
    const float* z = (const float*)d_in[0];
    const float* e = (const float*)d_in[1];
    char* ws = (char*)d_ws;
    uint8_t* zb = (uint8_t*)ws;                                          // 4 MB
    uint8_t* eb = (uint8_t*)(ws + ((size_t)4 << 20));                    // 4 MB
    float* zsq = (float*)(ws + ((size_t)8 << 20));                       // 16 KB
    float* esq = (float*)(ws + ((size_t)8 << 20) + 16384);               // 16 KB
    unsigned* min_enc = (unsigned*)(ws + ((size_t)8 << 20) + 32768);     // 16 KB

    prep_kernel<<<dim3(512), dim3(256), 0, stream>>>(
        z, e, zb, eb, zsq, esq, min_enc);
    gemm_min_kernel<<<dim3(32, 32), dim3(256), 0, stream>>>(
        zb, eb, zsq, min_enc);
    finalize_kernel<<<dim3(1), dim3(256), 0, stream>>>(min_enc, esq, (float*)d_out);
}